// Round 6
// baseline (726.156 us; speedup 1.0000x reference)
//
#include <hip/hip_runtime.h>
#include <hip/hip_bf16.h>
#include <cstdint>
#include <cstddef>

#define NN   100000
#define NE   1600000
#define HID  256
#define OUTC 40
#define NCH  16          // src-range chunks per row (chunk = src >> 13)

typedef __attribute__((ext_vector_type(8))) short bf16x8;
typedef __attribute__((ext_vector_type(4))) float f32x4;

static __device__ __forceinline__ ushort f2bf(float f) {
    __hip_bfloat16 h = __float2bfloat16(f);
    return *reinterpret_cast<ushort*>(&h);
}
static __device__ __forceinline__ float bflo(unsigned u) { return __uint_as_float(u << 16); }
static __device__ __forceinline__ float bfhi(unsigned u) { return __uint_as_float(u & 0xffff0000u); }
// signed byte k of word w -> float
static __device__ __forceinline__ float sb(unsigned w, int k) {
    return (float)((int)(w << (24 - 8 * k)) >> 24);
}

// ---------------- CSR build (src-chunk-bucketed per row) ----------------
__global__ void k_count16(const int* __restrict__ src, const int* __restrict__ dst,
                          int* __restrict__ cnt16) {
    int i = blockIdx.x * blockDim.x + threadIdx.x;
    if (i < NE) {
        int ch = src[i] >> 13;
        atomicAdd(&cnt16[dst[i] * NCH + ch], 1);
    }
}

__global__ void k_blocksum16(const int* __restrict__ cnt16, int* __restrict__ bsum) {
    __shared__ int s[256];
    int t = threadIdx.x;
    int n = blockIdx.x * 256 + t;
    int c = 0;
    if (n < NN) {
        const int4* p = (const int4*)(cnt16 + (size_t)n * NCH);
        #pragma unroll
        for (int w = 0; w < 4; ++w) { int4 v = p[w]; c += v.x + v.y + v.z + v.w; }
    }
    s[t] = c;
    __syncthreads();
    for (int off = 128; off; off >>= 1) {
        if (t < off) s[t] += s[t + off];
        __syncthreads();
    }
    if (t == 0) bsum[blockIdx.x] = s[0];
}

__global__ void k_scanblock(const int* __restrict__ bsum, int* __restrict__ boff, int nb) {
    __shared__ int s[512];
    int t = threadIdx.x;
    int v = (t < nb) ? bsum[t] : 0;
    s[t] = v;
    __syncthreads();
    for (int off = 1; off < 512; off <<= 1) {
        int u = (t >= off) ? s[t - off] : 0;
        __syncthreads();
        s[t] += u;
        __syncthreads();
    }
    if (t < nb) boff[t] = s[t] - v;
}

__global__ void k_rowptr16(const int* __restrict__ cnt16, const int* __restrict__ boff,
                           int* __restrict__ rowptr, int* __restrict__ fillp16,
                           float* __restrict__ invd) {
    __shared__ int s[256];
    int t = threadIdx.x;
    int n = blockIdx.x * 256 + t;
    int loc[NCH];
    int c = 0;
    if (n < NN) {
        const int4* p = (const int4*)(cnt16 + (size_t)n * NCH);
        #pragma unroll
        for (int w = 0; w < 4; ++w) {
            int4 v = p[w];
            loc[w*4+0] = v.x; loc[w*4+1] = v.y; loc[w*4+2] = v.z; loc[w*4+3] = v.w;
            c += v.x + v.y + v.z + v.w;
        }
    }
    s[t] = c;
    __syncthreads();
    for (int off = 1; off < 256; off <<= 1) {
        int u = (t >= off) ? s[t - off] : 0;
        __syncthreads();
        s[t] += u;
        __syncthreads();
    }
    if (n < NN) {
        int excl = boff[blockIdx.x] + s[t] - c;
        rowptr[n] = excl;
        invd[n]   = 1.0f / (float)(c > 1 ? c : 1);
        int run = excl;
        #pragma unroll
        for (int k = 0; k < NCH; ++k) { fillp16[(size_t)n * NCH + k] = run; run += loc[k]; }
    }
    if (n == 0) rowptr[NN] = NE;
}

__global__ void k_fill16(const int* __restrict__ src, const int* __restrict__ dst,
                         int* __restrict__ fillp16, int* __restrict__ colidx) {
    int i = blockIdx.x * blockDim.x + threadIdx.x;
    if (i < NE) {
        int s = src[i];
        int ch = s >> 13;
        int p = atomicAdd(&fillp16[(size_t)dst[i] * NCH + ch], 1);
        colidx[p] = s;
    }
}

// ---------------- fp32 -> bf16 conversion (weights) ----------------
__global__ void k_cvt4(const float* __restrict__ srcp, ushort* __restrict__ dstp, int n4) {
    int i = blockIdx.x * blockDim.x + threadIdx.x;
    if (i < n4) {
        float4 f = ((const float4*)srcp)[i];
        uint2 o;
        o.x = (unsigned)f2bf(f.x) | ((unsigned)f2bf(f.y) << 16);
        o.y = (unsigned)f2bf(f.z) | ((unsigned)f2bf(f.w) << 16);
        ((uint2*)dstp)[i] = o;
    }
}

// ---------------- per-row int8 quantization ----------------
__global__ __launch_bounds__(256) void k_quant_x(const float* __restrict__ x,
                                                 char* __restrict__ xq,
                                                 float* __restrict__ sx) {
    int t = threadIdx.x;
    int qw = t >> 4, ql = t & 15;
    int row = blockIdx.x * 16 + qw;
    if (row >= NN) return;
    const float4* p = (const float4*)(x + (size_t)row * 128 + ql * 8);
    float4 a = p[0], b = p[1];
    float v[8] = {a.x, a.y, a.z, a.w, b.x, b.y, b.z, b.w};
    float m = 0.f;
    #pragma unroll
    for (int k = 0; k < 8; ++k) m = fmaxf(m, fabsf(v[k]));
    m = fmaxf(m, __shfl_xor(m, 1));
    m = fmaxf(m, __shfl_xor(m, 2));
    m = fmaxf(m, __shfl_xor(m, 4));
    m = fmaxf(m, __shfl_xor(m, 8));
    float inv = (m > 0.f) ? 127.f / m : 0.f;
    unsigned w0 = 0, w1 = 0;
    #pragma unroll
    for (int k = 0; k < 4; ++k)
        w0 |= ((unsigned)(unsigned char)(char)(int)rintf(v[k] * inv)) << (8 * k);
    #pragma unroll
    for (int k = 0; k < 4; ++k)
        w1 |= ((unsigned)(unsigned char)(char)(int)rintf(v[4 + k] * inv)) << (8 * k);
    *(uint2*)(xq + (size_t)row * 128 + ql * 8) = make_uint2(w0, w1);
    if (ql == 0) sx[row] = m / 127.f;
}

__global__ __launch_bounds__(256) void k_quant_h(const ushort* __restrict__ h,
                                                 char* __restrict__ hq,
                                                 float* __restrict__ sh) {
    int t = threadIdx.x;
    int qw = t >> 4, ql = t & 15;
    int row = blockIdx.x * 16 + qw;
    if (row >= NN) return;
    const uint4* p = (const uint4*)(h + (size_t)row * 256 + ql * 16);
    uint4 a = p[0], b = p[1];
    float v[16];
    v[0]  = bflo(a.x); v[1]  = bfhi(a.x); v[2]  = bflo(a.y); v[3]  = bfhi(a.y);
    v[4]  = bflo(a.z); v[5]  = bfhi(a.z); v[6]  = bflo(a.w); v[7]  = bfhi(a.w);
    v[8]  = bflo(b.x); v[9]  = bfhi(b.x); v[10] = bflo(b.y); v[11] = bfhi(b.y);
    v[12] = bflo(b.z); v[13] = bfhi(b.z); v[14] = bflo(b.w); v[15] = bfhi(b.w);
    float m = 0.f;
    #pragma unroll
    for (int k = 0; k < 16; ++k) m = fmaxf(m, fabsf(v[k]));
    m = fmaxf(m, __shfl_xor(m, 1));
    m = fmaxf(m, __shfl_xor(m, 2));
    m = fmaxf(m, __shfl_xor(m, 4));
    m = fmaxf(m, __shfl_xor(m, 8));
    float inv = (m > 0.f) ? 127.f / m : 0.f;
    unsigned wo[4];
    #pragma unroll
    for (int wi = 0; wi < 4; ++wi) {
        unsigned w = 0;
        #pragma unroll
        for (int k = 0; k < 4; ++k)
            w |= ((unsigned)(unsigned char)(char)(int)rintf(v[wi * 4 + k] * inv)) << (8 * k);
        wo[wi] = w;
    }
    *(uint4*)(hq + (size_t)row * 256 + ql * 16) = make_uint4(wo[0], wo[1], wo[2], wo[3]);
    if (ql == 0) sh[row] = m / 127.f;
}

// ---------------- fused layer: int8 CSR mean-aggregate (LDS bf16) + dual bf16 MFMA GEMM ----------------
template<int D>
__global__ __launch_bounds__(256, 4) void k_layer8(
    const char* __restrict__ qin, const float* __restrict__ qs,
    const ushort* __restrict__ Wl, const ushort* __restrict__ Wr,
    const float* __restrict__ bias, const float* __restrict__ invd,
    const int* __restrict__ rowptr, const int* __restrict__ colidx,
    ushort* __restrict__ hout)        // [NN][HID] bf16, relu'd
{
    __shared__ ushort aggS[64 * D];
    char* aggSb = (char*)aggS;
    const int t  = threadIdx.x;
    const int r0 = blockIdx.x * 64;
    constexpr int LPR = D / 16;        // lanes per row (8 or 16)
    constexpr int GPB = 256 / LPR;     // rows in flight per block (32 or 16)
    const int gid = t / LPR, li = t % LPR;

    // ---- phase 1: mean-aggregate into LDS (bf16, 16B-granule XOR-swizzled) ----
    for (int rr = gid; rr < 64; rr += GPB) {
        const int r = r0 + rr;
        float acc[16];
        #pragma unroll
        for (int k = 0; k < 16; ++k) acc[k] = 0.f;
        if (r < NN) {
            const int beg = rowptr[r], end = rowptr[r + 1];
            for (int e = beg; e < end; e += 8) {
                int sidx[8];
                #pragma unroll
                for (int j = 0; j < 8; ++j) sidx[j] = (e + j < end) ? colidx[e + j] : -1;
                uint4 u[8]; float sc[8];
                #pragma unroll
                for (int j = 0; j < 8; ++j) {
                    if (sidx[j] >= 0) {
                        u[j]  = *(const uint4*)(qin + (size_t)sidx[j] * D + li * 16);
                        sc[j] = qs[sidx[j]];
                    } else { u[j] = make_uint4(0u, 0u, 0u, 0u); sc[j] = 0.f; }
                }
                #pragma unroll
                for (int j = 0; j < 8; ++j) {
                    #pragma unroll
                    for (int wi = 0; wi < 4; ++wi) {
                        unsigned w = (&u[j].x)[wi];
                        acc[wi*4+0] = fmaf(sc[j], sb(w, 0), acc[wi*4+0]);
                        acc[wi*4+1] = fmaf(sc[j], sb(w, 1), acc[wi*4+1]);
                        acc[wi*4+2] = fmaf(sc[j], sb(w, 2), acc[wi*4+2]);
                        acc[wi*4+3] = fmaf(sc[j], sb(w, 3), acc[wi*4+3]);
                    }
                }
            }
            const float iv = invd[r];
            #pragma unroll
            for (int k = 0; k < 16; ++k) acc[k] *= iv;
        }
        #pragma unroll
        for (int gg = 0; gg < 2; ++gg) {
            unsigned q0 = (unsigned)f2bf(acc[gg*8+0]) | ((unsigned)f2bf(acc[gg*8+1]) << 16);
            unsigned q1 = (unsigned)f2bf(acc[gg*8+2]) | ((unsigned)f2bf(acc[gg*8+3]) << 16);
            unsigned q2 = (unsigned)f2bf(acc[gg*8+4]) | ((unsigned)f2bf(acc[gg*8+5]) << 16);
            unsigned q3 = (unsigned)f2bf(acc[gg*8+6]) | ((unsigned)f2bf(acc[gg*8+7]) << 16);
            int g  = li * 2 + gg;
            int gs = g ^ (rr & 7);
            *(uint4*)(aggSb + (size_t)rr * (D * 2) + (gs << 4)) = make_uint4(q0, q1, q2, q3);
        }
    }
    __syncthreads();

    // ---- phase 2: per-wave 16-row MFMA GEMM over HID in 16-col chunks ----
    const int w = t >> 6, l = t & 63, lm = l & 15, lk = l >> 4;
    const int rr = w * 16 + lm;
    const int rg = r0 + rr;

    bf16x8 ax[D / 32];
    {
        const float sr = (rg < NN) ? qs[rg] : 0.f;
        #pragma unroll
        for (int kk = 0; kk < D / 32; ++kk) {
            uint2 uq = (rg < NN)
                ? *(const uint2*)(qin + (size_t)rg * D + kk * 32 + lk * 8)
                : make_uint2(0u, 0u);
            bf16x8 v;
            v[0] = (short)f2bf(sr * sb(uq.x, 0));
            v[1] = (short)f2bf(sr * sb(uq.x, 1));
            v[2] = (short)f2bf(sr * sb(uq.x, 2));
            v[3] = (short)f2bf(sr * sb(uq.x, 3));
            v[4] = (short)f2bf(sr * sb(uq.y, 0));
            v[5] = (short)f2bf(sr * sb(uq.y, 1));
            v[6] = (short)f2bf(sr * sb(uq.y, 2));
            v[7] = (short)f2bf(sr * sb(uq.y, 3));
            ax[kk] = v;
        }
    }

    for (int cc = 0; cc < HID / 16; ++cc) {
        const int c = cc * 16 + lm;
        f32x4 acc = {0.f, 0.f, 0.f, 0.f};
        #pragma unroll
        for (int kk = 0; kk < D / 32; ++kk) {
            int g  = kk * 4 + lk;
            int gs = g ^ (rr & 7);
            bf16x8 a_agg = *(const bf16x8*)(aggSb + (size_t)rr * (D * 2) + (gs << 4));
            bf16x8 bl = *(const bf16x8*)(Wl + (size_t)c * D + kk * 32 + lk * 8);
            bf16x8 br = *(const bf16x8*)(Wr + (size_t)c * D + kk * 32 + lk * 8);
            acc = __builtin_amdgcn_mfma_f32_16x16x32_bf16(a_agg, bl, acc, 0, 0, 0);
            acc = __builtin_amdgcn_mfma_f32_16x16x32_bf16(ax[kk], br, acc, 0, 0, 0);
        }
        const float bv = bias[c];
        #pragma unroll
        for (int i = 0; i < 4; ++i) {
            const int orow = r0 + w * 16 + lk * 4 + i;
            if (orow < NN) {
                float v = fmaxf(acc[i] + bv, 0.f);
                hout[(size_t)orow * HID + c] = f2bf(v);
            }
        }
    }
}

// ---------------- premul: q = int8(h1@Wlo^T) [N,64B rows]+sq, r = h1@Wro^T+bo [N,64] f32 ----------------
__global__ __launch_bounds__(256, 4) void k_premul(
    const ushort* __restrict__ h1, const ushort* __restrict__ wlo,
    const ushort* __restrict__ wro, const float* __restrict__ bo,
    char* __restrict__ qq, float* __restrict__ sq, float* __restrict__ rbuf)
{
    const int t = threadIdx.x;
    const int r0 = blockIdx.x * 64;
    const int w = t >> 6, l = t & 63, lm = l & 15, lk = l >> 4;
    const int rr = w * 16 + lm;
    const int rg = r0 + rr;

    f32x4 aq[3], ar[3];
    #pragma unroll
    for (int cc = 0; cc < 3; ++cc) { aq[cc] = {0.f,0.f,0.f,0.f}; ar[cc] = {0.f,0.f,0.f,0.f}; }

    #pragma unroll
    for (int kk = 0; kk < 8; ++kk) {
        bf16x8 a = (rg < NN)
            ? *(const bf16x8*)(h1 + (size_t)rg * 256 + kk * 32 + lk * 8)
            : (bf16x8)(short)0;
        #pragma unroll
        for (int cc = 0; cc < 3; ++cc) {
            const int c = cc * 16 + lm;
            bf16x8 bl = (c < OUTC) ? *(const bf16x8*)(wlo + (size_t)c * 256 + kk * 32 + lk * 8)
                                   : (bf16x8)(short)0;
            bf16x8 br = (c < OUTC) ? *(const bf16x8*)(wro + (size_t)c * 256 + kk * 32 + lk * 8)
                                   : (bf16x8)(short)0;
            aq[cc] = __builtin_amdgcn_mfma_f32_16x16x32_bf16(a, bl, aq[cc], 0, 0, 0);
            ar[cc] = __builtin_amdgcn_mfma_f32_16x16x32_bf16(a, br, ar[cc], 0, 0, 0);
        }
    }

    #pragma unroll
    for (int i = 0; i < 4; ++i) {
        const int orow = r0 + w * 16 + lk * 4 + i;
        if (orow >= NN) continue;
        float m = 0.f;
        #pragma unroll
        for (int cc = 0; cc < 3; ++cc) {
            const int c = cc * 16 + lm;
            if (c < OUTC) m = fmaxf(m, fabsf(aq[cc][i]));
        }
        m = fmaxf(m, __shfl_xor(m, 1));
        m = fmaxf(m, __shfl_xor(m, 2));
        m = fmaxf(m, __shfl_xor(m, 4));
        m = fmaxf(m, __shfl_xor(m, 8));
        const float inv = (m > 0.f) ? 127.f / m : 0.f;
        #pragma unroll
        for (int cc = 0; cc < 3; ++cc) {
            const int c = cc * 16 + lm;
            char qv = (c < OUTC) ? (char)(int)rintf(aq[cc][i] * inv) : (char)0;
            qq[(size_t)orow * 64 + c] = qv;
            rbuf[(size_t)orow * 64 + c] = (c < OUTC) ? (ar[cc][i] + bo[c]) : 0.f;
        }
        qq[(size_t)orow * 64 + 48 + lm] = (char)0;
        rbuf[(size_t)orow * 64 + 48 + lm] = 0.f;
        if (lm == 0) sq[orow] = m / 127.f;
    }
}

// ---------------- final: out = log_softmax(mean_agg(q) + r), 4 lanes per row ----------------
__global__ __launch_bounds__(256) void k_final(
    const char* __restrict__ qq, const float* __restrict__ sq,
    const float* __restrict__ rbuf, const float* __restrict__ invd,
    const int* __restrict__ rowptr, const int* __restrict__ colidx,
    float* __restrict__ out)
{
    const int t = threadIdx.x;
    const int g = t >> 2, li = t & 3;
    const int row = blockIdx.x * 64 + g;
    if (row >= NN) return;

    float acc[16];
    #pragma unroll
    for (int k = 0; k < 16; ++k) acc[k] = 0.f;

    const int beg = rowptr[row], end = rowptr[row + 1];
    for (int e = beg; e < end; e += 8) {
        int sidx[8];
        #pragma unroll
        for (int j = 0; j < 8; ++j) sidx[j] = (e + j < end) ? colidx[e + j] : -1;
        uint4 u[8]; float sc[8];
        #pragma unroll
        for (int j = 0; j < 8; ++j) {
            if (sidx[j] >= 0) {
                u[j]  = *(const uint4*)(qq + (size_t)sidx[j] * 64 + li * 16);
                sc[j] = sq[sidx[j]];
            } else { u[j] = make_uint4(0u, 0u, 0u, 0u); sc[j] = 0.f; }
        }
        #pragma unroll
        for (int j = 0; j < 8; ++j) {
            #pragma unroll
            for (int wi = 0; wi < 4; ++wi) {
                unsigned w = (&u[j].x)[wi];
                acc[wi*4+0] = fmaf(sc[j], sb(w, 0), acc[wi*4+0]);
                acc[wi*4+1] = fmaf(sc[j], sb(w, 1), acc[wi*4+1]);
                acc[wi*4+2] = fmaf(sc[j], sb(w, 2), acc[wi*4+2]);
                acc[wi*4+3] = fmaf(sc[j], sb(w, 3), acc[wi*4+3]);
            }
        }
    }

    const float iv = invd[row];
    const float4* rp = (const float4*)(rbuf + (size_t)row * 64 + li * 16);
    float v[16];
    #pragma unroll
    for (int ch = 0; ch < 4; ++ch) {
        float4 rv = rp[ch];
        v[ch*4+0] = acc[ch*4+0] * iv + rv.x;
        v[ch*4+1] = acc[ch*4+1] * iv + rv.y;
        v[ch*4+2] = acc[ch*4+2] * iv + rv.z;
        v[ch*4+3] = acc[ch*4+3] * iv + rv.w;
    }
    #pragma unroll
    for (int k = 0; k < 16; ++k)
        if (li * 16 + k >= OUTC) v[k] = -INFINITY;

    float m = v[0];
    #pragma unroll
    for (int k = 1; k < 16; ++k) m = fmaxf(m, v[k]);
    m = fmaxf(m, __shfl_xor(m, 1));
    m = fmaxf(m, __shfl_xor(m, 2));

    float s = 0.f;
    #pragma unroll
    for (int k = 0; k < 16; ++k)
        if (li * 16 + k < OUTC) s += __expf(v[k] - m);
    s += __shfl_xor(s, 1);
    s += __shfl_xor(s, 2);
    const float ls = __logf(s);

    #pragma unroll
    for (int ch = 0; ch < 4; ++ch) {
        const int c = li * 16 + ch * 4;
        if (c < OUTC) {
            float4 o;
            o.x = v[ch*4+0] - m - ls;
            o.y = v[ch*4+1] - m - ls;
            o.z = v[ch*4+2] - m - ls;
            o.w = v[ch*4+3] - m - ls;
            *(float4*)(out + (size_t)row * OUTC + c) = o;
        }
    }
}

extern "C" void kernel_launch(void* const* d_in, const int* in_sizes, int n_in,
                              void* d_out, int out_size, void* d_ws, size_t ws_size,
                              hipStream_t stream) {
    const float* x   = (const float*)d_in[0];
    const int*   ei  = (const int*)d_in[1];
    const int*   src = ei;
    const int*   dst = ei + NE;
    const float* Wl0 = (const float*)d_in[2];
    const float* Wr0 = (const float*)d_in[3];
    const float* b0  = (const float*)d_in[4];
    const float* Wl1 = (const float*)d_in[5];
    const float* Wr1 = (const float*)d_in[6];
    const float* b1  = (const float*)d_in[7];
    const float* Wlo = (const float*)d_in[8];
    const float* Wro = (const float*)d_in[9];
    const float* bo  = (const float*)d_in[10];
    float* out = (float*)d_out;

    char* ws = (char*)d_ws;
    const size_t MB = 1 << 20;
    float*  invd    = (float*)(ws + 0);
    int*    rowptr  = (int*)(ws + MB / 2);
    int*    bsum    = (int*)(ws + MB);
    int*    boff    = (int*)(ws + MB + MB / 4);
    float*  sx      = (float*)(ws + MB + MB / 2);
    float*  s0      = (float*)(ws + 2 * MB);
    float*  sq      = (float*)(ws + 2 * MB + MB / 2);
    ushort* Wb      = (ushort*)(ws + 3 * MB);
    int*    cnt16   = (int*)(ws + 4 * MB);                        // 6.4MB
    int*    fillp16 = (int*)(ws + 4 * MB + 6400000);              // 6.4MB
    int*    colidx  = (int*)(ws + 4 * MB + 12800000);             // 6.4MB -> ends ~23.4MB
    char*   xq      = (char*)(ws + 4 * MB);                       // 12.8MB (aliases cnt16+fillp16,
                                                                  //  both dead after k_fill16)
    ushort* h0      = (ushort*)(ws + 24 * MB);                    // [N,256] bf16 = 51.2MB (24..75.2)
    char*   h0q     = (char*)(ws + 76 * MB);                      // [N,256] int8 = 25.6MB (76..101.6)
    ushort* h1      = (ushort*)(ws + 24 * MB);                    // aliases h0 (dead after quant_h)
    char*   qq      = (char*)(ws + 4 * MB);                       // aliases xq (dead after layer0)
    float*  rbuf    = (float*)(ws + 76 * MB);                     // aliases h0q (dead after layer1)

    ushort* wl0 = Wb;
    ushort* wr0 = Wb + 32768;
    ushort* wl1 = Wb + 65536;
    ushort* wr1 = Wb + 131072;
    ushort* wlo = Wb + 196608;
    ushort* wro = Wb + 206848;

    // CSR build (src-chunk-bucketed neighbor lists)
    hipMemsetAsync(cnt16, 0, (size_t)NN * NCH * sizeof(int), stream);
    k_count16<<<(NE + 255) / 256, 256, 0, stream>>>(src, dst, cnt16);
    const int NB = (NN + 255) / 256;  // 391
    k_blocksum16<<<NB, 256, 0, stream>>>(cnt16, bsum);
    k_scanblock<<<1, 512, 0, stream>>>(bsum, boff, NB);
    k_rowptr16<<<NB, 256, 0, stream>>>(cnt16, boff, rowptr, fillp16, invd);
    k_fill16<<<(NE + 255) / 256, 256, 0, stream>>>(src, dst, fillp16, colidx);

    // weights -> bf16; x -> int8 (xq aliases cnt16/fillp16, so AFTER k_fill16)
    k_cvt4<<<(32768/4 + 255) / 256, 256, 0, stream>>>(Wl0, wl0, 32768/4);
    k_cvt4<<<(32768/4 + 255) / 256, 256, 0, stream>>>(Wr0, wr0, 32768/4);
    k_cvt4<<<(65536/4 + 255) / 256, 256, 0, stream>>>(Wl1, wl1, 65536/4);
    k_cvt4<<<(65536/4 + 255) / 256, 256, 0, stream>>>(Wr1, wr1, 65536/4);
    k_cvt4<<<(10240/4 + 255) / 256, 256, 0, stream>>>(Wlo, wlo, 10240/4);
    k_cvt4<<<(10240/4 + 255) / 256, 256, 0, stream>>>(Wro, wro, 10240/4);
    k_quant_x<<<(NN + 15) / 16, 256, 0, stream>>>(x, xq, sx);

    const int GB = (NN + 63) / 64;  // 1563
    // layer 0: xq int8 [N,128] -> h0 bf16 [N,256]
    k_layer8<128><<<GB, 256, 0, stream>>>(xq, sx, wl0, wr0, b0, invd, rowptr, colidx, h0);
    // quantize h0
    k_quant_h<<<(NN + 15) / 16, 256, 0, stream>>>(h0, h0q, s0);
    // layer 1: h0q int8 -> h1 bf16 (aliases h0 storage)
    k_layer8<256><<<GB, 256, 0, stream>>>(h0q, s0, wl1, wr1, b1, invd, rowptr, colidx, h1);
    // layer 2 restructured: premul (+int8 quant of q), then 1-line-per-edge gather + softmax
    k_premul<<<GB, 256, 0, stream>>>(h1, wlo, wro, bo, qq, sq, rbuf);
    k_final<<<(NN + 63) / 64, 256, 0, stream>>>(qq, sq, rbuf, invd, rowptr, colidx, out);
}

// Round 7
// 718.995 us; speedup vs baseline: 1.0100x; 1.0100x over previous
//
#include <hip/hip_runtime.h>
#include <hip/hip_bf16.h>
#include <cstdint>
#include <cstddef>

#define NN   100000
#define NE   1600000
#define HID  256
#define OUTC 40

typedef __attribute__((ext_vector_type(8))) short bf16x8;
typedef __attribute__((ext_vector_type(4))) float f32x4;

static __device__ __forceinline__ ushort f2bf(float f) {
    __hip_bfloat16 h = __float2bfloat16(f);
    return *reinterpret_cast<ushort*>(&h);
}
static __device__ __forceinline__ float bflo(unsigned u) { return __uint_as_float(u << 16); }
static __device__ __forceinline__ float bfhi(unsigned u) { return __uint_as_float(u & 0xffff0000u); }
// signed byte k of word w -> float
static __device__ __forceinline__ float sb(unsigned w, int k) {
    return (float)((int)(w << (24 - 8 * k)) >> 24);
}

// ---------------- CSR build (simple, round-5 proven) ----------------
__global__ void k_count(const int* __restrict__ dst, int* __restrict__ cnt) {
    int i = blockIdx.x * blockDim.x + threadIdx.x;
    if (i < NE) atomicAdd(&cnt[dst[i]], 1);
}

__global__ void k_blocksum(const int* __restrict__ cnt, int* __restrict__ bsum) {
    __shared__ int s[256];
    int t = threadIdx.x;
    int n = blockIdx.x * 256 + t;
    s[t] = (n < NN) ? cnt[n] : 0;
    __syncthreads();
    for (int off = 128; off; off >>= 1) {
        if (t < off) s[t] += s[t + off];
        __syncthreads();
    }
    if (t == 0) bsum[blockIdx.x] = s[0];
}

__global__ void k_scanblock(const int* __restrict__ bsum, int* __restrict__ boff, int nb) {
    __shared__ int s[512];
    int t = threadIdx.x;
    int v = (t < nb) ? bsum[t] : 0;
    s[t] = v;
    __syncthreads();
    for (int off = 1; off < 512; off <<= 1) {
        int u = (t >= off) ? s[t - off] : 0;
        __syncthreads();
        s[t] += u;
        __syncthreads();
    }
    if (t < nb) boff[t] = s[t] - v;
}

__global__ void k_rowptr(const int* __restrict__ cnt, const int* __restrict__ boff,
                         int* __restrict__ rowptr, int* __restrict__ fillp,
                         float* __restrict__ invd) {
    __shared__ int s[256];
    int t = threadIdx.x;
    int n = blockIdx.x * 256 + t;
    int c = (n < NN) ? cnt[n] : 0;
    s[t] = c;
    __syncthreads();
    for (int off = 1; off < 256; off <<= 1) {
        int u = (t >= off) ? s[t - off] : 0;
        __syncthreads();
        s[t] += u;
        __syncthreads();
    }
    if (n < NN) {
        int excl = boff[blockIdx.x] + s[t] - c;
        rowptr[n] = excl;
        fillp[n]  = excl;
        invd[n]   = 1.0f / (float)(c > 1 ? c : 1);
    }
    if (n == 0) rowptr[NN] = NE;
}

__global__ void k_fill(const int* __restrict__ src, const int* __restrict__ dst,
                       int* __restrict__ fillp, int* __restrict__ colidx) {
    int i = blockIdx.x * blockDim.x + threadIdx.x;
    if (i < NE) {
        int p = atomicAdd(&fillp[dst[i]], 1);
        colidx[p] = src[i];
    }
}

// ---------------- fp32 -> bf16 conversion (weights) ----------------
__global__ void k_cvt4(const float* __restrict__ srcp, ushort* __restrict__ dstp, int n4) {
    int i = blockIdx.x * blockDim.x + threadIdx.x;
    if (i < n4) {
        float4 f = ((const float4*)srcp)[i];
        uint2 o;
        o.x = (unsigned)f2bf(f.x) | ((unsigned)f2bf(f.y) << 16);
        o.y = (unsigned)f2bf(f.z) | ((unsigned)f2bf(f.w) << 16);
        ((uint2*)dstp)[i] = o;
    }
}

// ---------------- x fp32 [N,128] -> signed int4 (scale=rowmax/7) ----------------
__global__ __launch_bounds__(256) void k_quant_x4(const float* __restrict__ x,
                                                  unsigned* __restrict__ xq4,
                                                  float* __restrict__ sx4) {
    int t = threadIdx.x;
    int qw = t >> 4, ql = t & 15;
    int row = blockIdx.x * 16 + qw;
    if (row >= NN) return;
    const float4* p = (const float4*)(x + (size_t)row * 128 + ql * 8);
    float4 a = p[0], b = p[1];
    float v[8] = {a.x, a.y, a.z, a.w, b.x, b.y, b.z, b.w};
    float m = 0.f;
    #pragma unroll
    for (int k = 0; k < 8; ++k) m = fmaxf(m, fabsf(v[k]));
    m = fmaxf(m, __shfl_xor(m, 1));
    m = fmaxf(m, __shfl_xor(m, 2));
    m = fmaxf(m, __shfl_xor(m, 4));
    m = fmaxf(m, __shfl_xor(m, 8));
    float inv = (m > 0.f) ? 7.f / m : 0.f;
    unsigned w = 0;
    #pragma unroll
    for (int k = 0; k < 8; ++k)
        w |= ((unsigned)(int)rintf(v[k] * inv) & 15u) << (4 * k);
    xq4[(size_t)row * 16 + ql] = w;
    if (ql == 0) sx4[row] = (m > 0.f) ? m / 7.f : 0.f;
}

// ---------------- h0 bf16 [N,256] (>=0) -> int8 (self) + unsigned int4 (gather) ----------------
__global__ __launch_bounds__(256) void k_quant_h84(const ushort* __restrict__ h,
                                                   char* __restrict__ hq8, float* __restrict__ s8,
                                                   unsigned* __restrict__ hq4, float* __restrict__ s4) {
    int t = threadIdx.x;
    int qw = t >> 4, ql = t & 15;
    int row = blockIdx.x * 16 + qw;
    if (row >= NN) return;
    const uint4* p = (const uint4*)(h + (size_t)row * 256 + ql * 16);
    uint4 a = p[0], b = p[1];
    float v[16];
    v[0]  = bflo(a.x); v[1]  = bfhi(a.x); v[2]  = bflo(a.y); v[3]  = bfhi(a.y);
    v[4]  = bflo(a.z); v[5]  = bfhi(a.z); v[6]  = bflo(a.w); v[7]  = bfhi(a.w);
    v[8]  = bflo(b.x); v[9]  = bfhi(b.x); v[10] = bflo(b.y); v[11] = bfhi(b.y);
    v[12] = bflo(b.z); v[13] = bfhi(b.z); v[14] = bflo(b.w); v[15] = bfhi(b.w);
    float m = 0.f;
    #pragma unroll
    for (int k = 0; k < 16; ++k) m = fmaxf(m, v[k]);   // h >= 0
    m = fmaxf(m, __shfl_xor(m, 1));
    m = fmaxf(m, __shfl_xor(m, 2));
    m = fmaxf(m, __shfl_xor(m, 4));
    m = fmaxf(m, __shfl_xor(m, 8));
    float inv8 = (m > 0.f) ? 127.f / m : 0.f;
    float inv4 = (m > 0.f) ? 15.f / m : 0.f;
    unsigned wo[4];
    #pragma unroll
    for (int wi = 0; wi < 4; ++wi) {
        unsigned w = 0;
        #pragma unroll
        for (int k = 0; k < 4; ++k)
            w |= ((unsigned)(unsigned char)(char)(int)rintf(v[wi * 4 + k] * inv8)) << (8 * k);
        wo[wi] = w;
    }
    *(uint4*)(hq8 + (size_t)row * 256 + ql * 16) = make_uint4(wo[0], wo[1], wo[2], wo[3]);
    uint2 n4;
    unsigned lo = 0, hi = 0;
    #pragma unroll
    for (int k = 0; k < 8; ++k)
        lo |= ((unsigned)(int)rintf(v[k] * inv4) & 15u) << (4 * k);
    #pragma unroll
    for (int k = 0; k < 8; ++k)
        hi |= ((unsigned)(int)rintf(v[8 + k] * inv4) & 15u) << (4 * k);
    n4.x = lo; n4.y = hi;
    *(uint2*)(hq4 + (size_t)row * 32 + ql * 2) = n4;
    if (ql == 0) {
        s8[row] = (m > 0.f) ? m / 127.f : 0.f;
        s4[row] = (m > 0.f) ? m / 15.f  : 0.f;
    }
}

// ---------------- fused layer: int4 CSR mean-aggregate (LDS bf16) + dual bf16 MFMA GEMM ----------------
// qin4: [NN][D/8] words of packed nibbles + per-row scale qs4. D/16 lanes per row,
// 16 features (8B uint2) per lane, predicated 8-edge batches.
// Self term: SELF_F32 ? x fp32 rows : int8 rows (selfp) + scale selfs.
template<int D, bool SELF_F32, bool SIGNED>
__global__ __launch_bounds__(256, 4) void k_layer4(
    const unsigned* __restrict__ qin4, const float* __restrict__ qs4,
    const void* __restrict__ selfp, const float* __restrict__ selfs,
    const ushort* __restrict__ Wl, const ushort* __restrict__ Wr,
    const float* __restrict__ bias, const float* __restrict__ invd,
    const int* __restrict__ rowptr, const int* __restrict__ colidx,
    ushort* __restrict__ hout)        // [NN][HID] bf16, relu'd
{
    __shared__ ushort aggS[64 * D];
    char* aggSb = (char*)aggS;
    const int t  = threadIdx.x;
    const int r0 = blockIdx.x * 64;
    constexpr int LPR = D / 16;        // lanes per row (8 or 16)
    constexpr int GPB = 256 / LPR;     // row-groups per block (32 or 16)
    constexpr int RW  = D / 8;         // words per row
    const int gid = t / LPR, li = t % LPR;

    // ---- phase 1: mean-aggregate into LDS (bf16, 16B-granule XOR-swizzled) ----
    for (int rr = gid; rr < 64; rr += GPB) {
        const int r = r0 + rr;
        float acc[16];
        #pragma unroll
        for (int k = 0; k < 16; ++k) acc[k] = 0.f;
        if (r < NN) {
            const int beg = rowptr[r], end = rowptr[r + 1];
            for (int e = beg; e < end; e += 8) {
                int sidx[8];
                #pragma unroll
                for (int j = 0; j < 8; ++j) sidx[j] = (e + j < end) ? colidx[e + j] : -1;
                uint2 u[8]; float sc[8];
                #pragma unroll
                for (int j = 0; j < 8; ++j) {
                    if (sidx[j] >= 0) {
                        u[j]  = *(const uint2*)(qin4 + (size_t)sidx[j] * RW + li * 2);
                        sc[j] = qs4[sidx[j]];
                    } else { u[j] = make_uint2(0u, 0u); sc[j] = 0.f; }
                }
                #pragma unroll
                for (int j = 0; j < 8; ++j) {
                    #pragma unroll
                    for (int wi = 0; wi < 2; ++wi) {
                        unsigned w = wi ? u[j].y : u[j].x;
                        #pragma unroll
                        for (int k = 0; k < 8; ++k) {
                            float f;
                            if (SIGNED) f = (float)((int)(w << (28 - 4 * k)) >> 28);
                            else        f = (float)((w >> (4 * k)) & 15u);
                            acc[wi * 8 + k] = fmaf(sc[j], f, acc[wi * 8 + k]);
                        }
                    }
                }
            }
            const float iv = invd[r];
            #pragma unroll
            for (int k = 0; k < 16; ++k) acc[k] *= iv;
        }
        #pragma unroll
        for (int gg = 0; gg < 2; ++gg) {
            unsigned q0 = (unsigned)f2bf(acc[gg*8+0]) | ((unsigned)f2bf(acc[gg*8+1]) << 16);
            unsigned q1 = (unsigned)f2bf(acc[gg*8+2]) | ((unsigned)f2bf(acc[gg*8+3]) << 16);
            unsigned q2 = (unsigned)f2bf(acc[gg*8+4]) | ((unsigned)f2bf(acc[gg*8+5]) << 16);
            unsigned q3 = (unsigned)f2bf(acc[gg*8+6]) | ((unsigned)f2bf(acc[gg*8+7]) << 16);
            int g  = li * 2 + gg;
            int gs = g ^ (rr & 7);
            *(uint4*)(aggSb + (size_t)rr * (D * 2) + (gs << 4)) = make_uint4(q0, q1, q2, q3);
        }
    }
    __syncthreads();

    // ---- phase 2: per-wave 16-row MFMA GEMM over HID in 16-col chunks ----
    const int w = t >> 6, l = t & 63, lm = l & 15, lk = l >> 4;
    const int rr = w * 16 + lm;
    const int rg = r0 + rr;

    bf16x8 ax[D / 32];
    if (SELF_F32) {
        const float* xf = (const float*)selfp;
        #pragma unroll
        for (int kk = 0; kk < D / 32; ++kk) {
            bf16x8 v;
            if (rg < NN) {
                const float4* p = (const float4*)(xf + (size_t)rg * D + kk * 32 + lk * 8);
                float4 f0 = p[0], f1 = p[1];
                v[0] = (short)f2bf(f0.x); v[1] = (short)f2bf(f0.y);
                v[2] = (short)f2bf(f0.z); v[3] = (short)f2bf(f0.w);
                v[4] = (short)f2bf(f1.x); v[5] = (short)f2bf(f1.y);
                v[6] = (short)f2bf(f1.z); v[7] = (short)f2bf(f1.w);
            } else v = (bf16x8)(short)0;
            ax[kk] = v;
        }
    } else {
        const char* hq = (const char*)selfp;
        const float sr = (rg < NN) ? selfs[rg] : 0.f;
        #pragma unroll
        for (int kk = 0; kk < D / 32; ++kk) {
            uint2 uq = (rg < NN)
                ? *(const uint2*)(hq + (size_t)rg * D + kk * 32 + lk * 8)
                : make_uint2(0u, 0u);
            bf16x8 v;
            v[0] = (short)f2bf(sr * sb(uq.x, 0));
            v[1] = (short)f2bf(sr * sb(uq.x, 1));
            v[2] = (short)f2bf(sr * sb(uq.x, 2));
            v[3] = (short)f2bf(sr * sb(uq.x, 3));
            v[4] = (short)f2bf(sr * sb(uq.y, 0));
            v[5] = (short)f2bf(sr * sb(uq.y, 1));
            v[6] = (short)f2bf(sr * sb(uq.y, 2));
            v[7] = (short)f2bf(sr * sb(uq.y, 3));
            ax[kk] = v;
        }
    }

    for (int cc = 0; cc < HID / 16; ++cc) {
        const int c = cc * 16 + lm;
        f32x4 acc = {0.f, 0.f, 0.f, 0.f};
        #pragma unroll
        for (int kk = 0; kk < D / 32; ++kk) {
            int g  = kk * 4 + lk;
            int gs = g ^ (rr & 7);
            bf16x8 a_agg = *(const bf16x8*)(aggSb + (size_t)rr * (D * 2) + (gs << 4));
            bf16x8 bl = *(const bf16x8*)(Wl + (size_t)c * D + kk * 32 + lk * 8);
            bf16x8 br = *(const bf16x8*)(Wr + (size_t)c * D + kk * 32 + lk * 8);
            acc = __builtin_amdgcn_mfma_f32_16x16x32_bf16(a_agg, bl, acc, 0, 0, 0);
            acc = __builtin_amdgcn_mfma_f32_16x16x32_bf16(ax[kk], br, acc, 0, 0, 0);
        }
        const float bv = bias[c];
        #pragma unroll
        for (int i = 0; i < 4; ++i) {
            const int orow = r0 + w * 16 + lk * 4 + i;
            if (orow < NN) {
                float v = fmaxf(acc[i] + bv, 0.f);
                hout[(size_t)orow * HID + c] = f2bf(v);
            }
        }
    }
}

// ---------------- premul: q = int8(h1@Wlo^T) [N,64B rows]+sq, r = h1@Wro^T+bo [N,64] f32 ----------------
__global__ __launch_bounds__(256, 4) void k_premul(
    const ushort* __restrict__ h1, const ushort* __restrict__ wlo,
    const ushort* __restrict__ wro, const float* __restrict__ bo,
    char* __restrict__ qq, float* __restrict__ sq, float* __restrict__ rbuf)
{
    const int t = threadIdx.x;
    const int r0 = blockIdx.x * 64;
    const int w = t >> 6, l = t & 63, lm = l & 15, lk = l >> 4;
    const int rr = w * 16 + lm;
    const int rg = r0 + rr;

    f32x4 aq[3], ar[3];
    #pragma unroll
    for (int cc = 0; cc < 3; ++cc) { aq[cc] = {0.f,0.f,0.f,0.f}; ar[cc] = {0.f,0.f,0.f,0.f}; }

    #pragma unroll
    for (int kk = 0; kk < 8; ++kk) {
        bf16x8 a = (rg < NN)
            ? *(const bf16x8*)(h1 + (size_t)rg * 256 + kk * 32 + lk * 8)
            : (bf16x8)(short)0;
        #pragma unroll
        for (int cc = 0; cc < 3; ++cc) {
            const int c = cc * 16 + lm;
            bf16x8 bl = (c < OUTC) ? *(const bf16x8*)(wlo + (size_t)c * 256 + kk * 32 + lk * 8)
                                   : (bf16x8)(short)0;
            bf16x8 br = (c < OUTC) ? *(const bf16x8*)(wro + (size_t)c * 256 + kk * 32 + lk * 8)
                                   : (bf16x8)(short)0;
            aq[cc] = __builtin_amdgcn_mfma_f32_16x16x32_bf16(a, bl, aq[cc], 0, 0, 0);
            ar[cc] = __builtin_amdgcn_mfma_f32_16x16x32_bf16(a, br, ar[cc], 0, 0, 0);
        }
    }

    #pragma unroll
    for (int i = 0; i < 4; ++i) {
        const int orow = r0 + w * 16 + lk * 4 + i;
        if (orow >= NN) continue;
        float m = 0.f;
        #pragma unroll
        for (int cc = 0; cc < 3; ++cc) {
            const int c = cc * 16 + lm;
            if (c < OUTC) m = fmaxf(m, fabsf(aq[cc][i]));
        }
        m = fmaxf(m, __shfl_xor(m, 1));
        m = fmaxf(m, __shfl_xor(m, 2));
        m = fmaxf(m, __shfl_xor(m, 4));
        m = fmaxf(m, __shfl_xor(m, 8));
        const float inv = (m > 0.f) ? 127.f / m : 0.f;
        #pragma unroll
        for (int cc = 0; cc < 3; ++cc) {
            const int c = cc * 16 + lm;
            char qv = (c < OUTC) ? (char)(int)rintf(aq[cc][i] * inv) : (char)0;
            qq[(size_t)orow * 64 + c] = qv;
            rbuf[(size_t)orow * 64 + c] = (c < OUTC) ? (ar[cc][i] + bo[c]) : 0.f;
        }
        qq[(size_t)orow * 64 + 48 + lm] = (char)0;
        rbuf[(size_t)orow * 64 + 48 + lm] = 0.f;
        if (lm == 0) sq[orow] = m / 127.f;
    }
}

// ---------------- final: out = log_softmax(mean_agg(q) + r), 4 lanes per row ----------------
__global__ __launch_bounds__(256) void k_final(
    const char* __restrict__ qq, const float* __restrict__ sq,
    const float* __restrict__ rbuf, const float* __restrict__ invd,
    const int* __restrict__ rowptr, const int* __restrict__ colidx,
    float* __restrict__ out)
{
    const int t = threadIdx.x;
    const int g = t >> 2, li = t & 3;
    const int row = blockIdx.x * 64 + g;
    if (row >= NN) return;

    float acc[16];
    #pragma unroll
    for (int k = 0; k < 16; ++k) acc[k] = 0.f;

    const int beg = rowptr[row], end = rowptr[row + 1];
    for (int e = beg; e < end; e += 8) {
        int sidx[8];
        #pragma unroll
        for (int j = 0; j < 8; ++j) sidx[j] = (e + j < end) ? colidx[e + j] : -1;
        uint4 u[8]; float sc[8];
        #pragma unroll
        for (int j = 0; j < 8; ++j) {
            if (sidx[j] >= 0) {
                u[j]  = *(const uint4*)(qq + (size_t)sidx[j] * 64 + li * 16);
                sc[j] = sq[sidx[j]];
            } else { u[j] = make_uint4(0u, 0u, 0u, 0u); sc[j] = 0.f; }
        }
        #pragma unroll
        for (int j = 0; j < 8; ++j) {
            #pragma unroll
            for (int wi = 0; wi < 4; ++wi) {
                unsigned w = (&u[j].x)[wi];
                acc[wi*4+0] = fmaf(sc[j], sb(w, 0), acc[wi*4+0]);
                acc[wi*4+1] = fmaf(sc[j], sb(w, 1), acc[wi*4+1]);
                acc[wi*4+2] = fmaf(sc[j], sb(w, 2), acc[wi*4+2]);
                acc[wi*4+3] = fmaf(sc[j], sb(w, 3), acc[wi*4+3]);
            }
        }
    }

    const float iv = invd[row];
    const float4* rp = (const float4*)(rbuf + (size_t)row * 64 + li * 16);
    float v[16];
    #pragma unroll
    for (int ch = 0; ch < 4; ++ch) {
        float4 rv = rp[ch];
        v[ch*4+0] = acc[ch*4+0] * iv + rv.x;
        v[ch*4+1] = acc[ch*4+1] * iv + rv.y;
        v[ch*4+2] = acc[ch*4+2] * iv + rv.z;
        v[ch*4+3] = acc[ch*4+3] * iv + rv.w;
    }
    #pragma unroll
    for (int k = 0; k < 16; ++k)
        if (li * 16 + k >= OUTC) v[k] = -INFINITY;

    float m = v[0];
    #pragma unroll
    for (int k = 1; k < 16; ++k) m = fmaxf(m, v[k]);
    m = fmaxf(m, __shfl_xor(m, 1));
    m = fmaxf(m, __shfl_xor(m, 2));

    float s = 0.f;
    #pragma unroll
    for (int k = 0; k < 16; ++k)
        if (li * 16 + k < OUTC) s += __expf(v[k] - m);
    s += __shfl_xor(s, 1);
    s += __shfl_xor(s, 2);
    const float ls = __logf(s);

    #pragma unroll
    for (int ch = 0; ch < 4; ++ch) {
        const int c = li * 16 + ch * 4;
        if (c < OUTC) {
            float4 o;
            o.x = v[ch*4+0] - m - ls;
            o.y = v[ch*4+1] - m - ls;
            o.z = v[ch*4+2] - m - ls;
            o.w = v[ch*4+3] - m - ls;
            *(float4*)(out + (size_t)row * OUTC + c) = o;
        }
    }
}

extern "C" void kernel_launch(void* const* d_in, const int* in_sizes, int n_in,
                              void* d_out, int out_size, void* d_ws, size_t ws_size,
                              hipStream_t stream) {
    const float* x   = (const float*)d_in[0];
    const int*   ei  = (const int*)d_in[1];
    const int*   src = ei;
    const int*   dst = ei + NE;
    const float* Wl0 = (const float*)d_in[2];
    const float* Wr0 = (const float*)d_in[3];
    const float* b0  = (const float*)d_in[4];
    const float* Wl1 = (const float*)d_in[5];
    const float* Wr1 = (const float*)d_in[6];
    const float* b1  = (const float*)d_in[7];
    const float* Wlo = (const float*)d_in[8];
    const float* Wro = (const float*)d_in[9];
    const float* bo  = (const float*)d_in[10];
    float* out = (float*)d_out;

    char* ws = (char*)d_ws;
    const size_t MB = 1 << 20;
    float*    invd   = (float*)(ws + 0);
    int*      rowptr = (int*)(ws + MB / 2);
    int*      cnt    = (int*)(ws + MB);
    int*      fillp  = (int*)(ws + MB + MB / 2);
    int*      bsum   = (int*)(ws + 2 * MB);
    int*      boff   = (int*)(ws + 2 * MB + MB / 4);
    float*    sx4    = (float*)(ws + 2 * MB + MB / 2);
    float*    s8     = (float*)(ws + 3 * MB);
    float*    s4     = (float*)(ws + 3 * MB + MB / 2);
    float*    sq     = (float*)(ws + 4 * MB);
    ushort*   Wb     = (ushort*)(ws + 4 * MB + MB / 2);
    int*      colidx = (int*)(ws + 5 * MB + MB / 2);     // 6.4MB -> ends ~11.9
    unsigned* xq4    = (unsigned*)(ws + 12 * MB);        // [N][64B] = 6.4MB (12..18.4)
    char*     qq     = (char*)(ws + 12 * MB);            // aliases xq4 (dead after layer0)
    unsigned* h0q4   = (unsigned*)(ws + 19 * MB);        // [N][128B] = 12.8MB (19..31.8)
    ushort*   h0     = (ushort*)(ws + 32 * MB);          // [N,256] bf16 = 51.2MB (32..83.2)
    ushort*   h1     = (ushort*)(ws + 32 * MB);          // aliases h0 (self reads h0q8, not h0)
    char*     h0q8   = (char*)(ws + 84 * MB);            // [N,256] int8 = 25.6MB (84..109.6)
    float*    rbuf   = (float*)(ws + 84 * MB);           // aliases h0q8 (dead after layer1)

    ushort* wl0 = Wb;
    ushort* wr0 = Wb + 32768;
    ushort* wl1 = Wb + 65536;
    ushort* wr1 = Wb + 131072;
    ushort* wlo = Wb + 196608;
    ushort* wro = Wb + 206848;

    // CSR build
    hipMemsetAsync(cnt, 0, NN * sizeof(int), stream);
    k_count<<<(NE + 255) / 256, 256, 0, stream>>>(dst, cnt);
    const int NB = (NN + 255) / 256;  // 391
    k_blocksum<<<NB, 256, 0, stream>>>(cnt, bsum);
    k_scanblock<<<1, 512, 0, stream>>>(bsum, boff, NB);
    k_rowptr<<<NB, 256, 0, stream>>>(cnt, boff, rowptr, fillp, invd);
    k_fill<<<(NE + 255) / 256, 256, 0, stream>>>(src, dst, fillp, colidx);

    // weights -> bf16; x -> int4
    k_cvt4<<<(32768/4 + 255) / 256, 256, 0, stream>>>(Wl0, wl0, 32768/4);
    k_cvt4<<<(32768/4 + 255) / 256, 256, 0, stream>>>(Wr0, wr0, 32768/4);
    k_cvt4<<<(65536/4 + 255) / 256, 256, 0, stream>>>(Wl1, wl1, 65536/4);
    k_cvt4<<<(65536/4 + 255) / 256, 256, 0, stream>>>(Wr1, wr1, 65536/4);
    k_cvt4<<<(10240/4 + 255) / 256, 256, 0, stream>>>(Wlo, wlo, 10240/4);
    k_cvt4<<<(10240/4 + 255) / 256, 256, 0, stream>>>(Wro, wro, 10240/4);
    k_quant_x4<<<(NN + 15) / 16, 256, 0, stream>>>(x, xq4, sx4);

    const int GB = (NN + 63) / 64;  // 1563
    // layer 0: gather int4 x (1 line/edge), self fp32 x -> h0 bf16
    k_layer4<128, true, true><<<GB, 256, 0, stream>>>(
        xq4, sx4, x, nullptr, wl0, wr0, b0, invd, rowptr, colidx, h0);
    // quantize h0 -> int8 (self) + int4 (gather)
    k_quant_h84<<<(NN + 15) / 16, 256, 0, stream>>>(h0, h0q8, s8, h0q4, s4);
    // layer 1: gather int4 h0 (2 lines/edge), self int8 h0 -> h1 bf16 (aliases h0)
    k_layer4<256, false, false><<<GB, 256, 0, stream>>>(
        h0q4, s4, h0q8, s8, wl1, wr1, b1, invd, rowptr, colidx, h1);
    // layer 2 restructured: premul (+int8 quant of q), then 1-line-per-edge gather + softmax
    k_premul<<<GB, 256, 0, stream>>>(h1, wlo, wro, bo, qq, sq, rbuf);
    k_final<<<(NN + 63) / 64, 256, 0, stream>>>(qq, sq, rbuf, invd, rowptr, colidx, out);
}